// Round 8
// baseline (525.697 us; speedup 1.0000x reference)
//
#include <hip/hip_runtime.h>
#include <hip/hip_bf16.h>

#define NN 100000
#define NE 1600000
#define D 128
#define NGRP 8
#define GSZ (NN / NGRP)        // 12500, exact
#define BCAP 208896            // bucket capacity (NE/8=200000 + 19-sigma slack)
#define WSTRIDE 136            // LDS row stride (u16): 272B -> conflict-free b128

typedef unsigned short u16;
typedef unsigned int u32;
typedef unsigned long long u64;
typedef __attribute__((ext_vector_type(8))) short bf16x8;
typedef __attribute__((ext_vector_type(4))) float f32x4;
typedef __attribute__((ext_vector_type(8))) u16 u16x8;

__device__ inline u16 f2b(float f) {
  union { float f; u32 u; } v; v.f = f;
  u32 u = v.u;
  return (u16)((u + 0x7fffu + ((u >> 16) & 1u)) >> 16);
}
__device__ inline float b2f(u16 h) {
  union { u32 u; float f; } v; v.u = ((u32)h) << 16; return v.f;
}

// ---------------- x -> bf16 convert, pure streaming -------------------------
__global__ __launch_bounds__(256) void k_cvt(const float* __restrict__ xin,
                                             u16* __restrict__ xb) {
  int e = blockIdx.x * 256 + threadIdx.x;      // 1.6M exactly
  const f32x4* p = reinterpret_cast<const f32x4*>(xin) + (size_t)e * 2;
  f32x4 a = __builtin_nontemporal_load(p);
  f32x4 b = __builtin_nontemporal_load(p + 1);
  u16x8 o;
  o[0] = f2b(a[0]); o[1] = f2b(a[1]); o[2] = f2b(a[2]); o[3] = f2b(a[3]);
  o[4] = f2b(b[0]); o[5] = f2b(b[1]); o[6] = f2b(b[2]); o[7] = f2b(b[3]);
  __builtin_nontemporal_store(o, reinterpret_cast<u16x8*>(xb + (size_t)e * 8));
}

// ---------------- phase A: bin edges into 8 dst-group buckets ---------------
// streaming read, near-sequential bucket writes. one atomic per bucket per
// wave (counters padded to separate cache lines).
#define EPT 8
__global__ __launch_bounds__(256) void k_part(const int* __restrict__ src,
    const int* __restrict__ dst, u64* __restrict__ bkt, int* __restrict__ bcur) {
  const int t = threadIdx.x, lane = t & 63;
  const int eb = blockIdx.x * (256 * EPT);
  int q[EPT]; u32 pd[EPT], ps[EPT];
  #pragma unroll
  for (int r = 0; r < EPT; ++r) {
    int e = eb + r * 256 + t;
    bool v = e < NE;
    int d = v ? __builtin_nontemporal_load(&dst[e]) : 0;
    int s = v ? __builtin_nontemporal_load(&src[e]) : 0;
    q[r] = v ? d / GSZ : 8;
    pd[r] = (u32)d; ps[r] = (u32)s;
  }
  u64 below = (lane == 63) ? 0x7fffffffffffffffull : ((1ull << lane) - 1);
  int base[NGRP];
  #pragma unroll
  for (int b = 0; b < NGRP; ++b) {
    int cnt = 0;
    #pragma unroll
    for (int r = 0; r < EPT; ++r) cnt += __popcll(__ballot(q[r] == b));
    int bs = 0;
    if (lane == 0 && cnt) bs = atomicAdd(&bcur[b * 16], cnt);
    base[b] = __shfl(bs, 0, 64);
  }
  #pragma unroll
  for (int b = 0; b < NGRP; ++b) {
    int run = 0;
    #pragma unroll
    for (int r = 0; r < EPT; ++r) {
      u64 m = __ballot(q[r] == b);
      if (q[r] == b) {
        int pos = base[b] + run + __popcll(m & below);
        if (pos < BCAP)
          bkt[(size_t)b * BCAP + pos] = ((u64)pd[r] << 32) | ps[r];
      }
      run += __popcll(m);
    }
  }
}

// ---------------- deg count from buckets: XCD-local atomics -----------------
__global__ __launch_bounds__(256) void k_degcnt(const u64* __restrict__ bkt,
    const int* __restrict__ bcur, int* __restrict__ deg) {
  int g = blockIdx.x & (NGRP - 1);
  int cnt = bcur[g * 16]; if (cnt > BCAP) cnt = BCAP;
  int e0 = (blockIdx.x >> 3) * 2048 + threadIdx.x;
  #pragma unroll
  for (int r = 0; r < 8; ++r) {
    int i = e0 + r * 256;
    if (i < cnt) {
      int d = (int)(__builtin_nontemporal_load(&bkt[(size_t)g * BCAP + i]) >> 32);
      atomicAdd(&deg[d], 1);
    }
  }
}

__global__ void k_scan1(const int* __restrict__ deg, int* __restrict__ incl,
                        int* __restrict__ bsum) {
  __shared__ int s[256];
  int t = threadIdx.x;
  int i = blockIdx.x * 256 + t;
  int v = (i < NN) ? deg[i] : 0;
  s[t] = v; __syncthreads();
  for (int off = 1; off < 256; off <<= 1) {
    int u = (t >= off) ? s[t - off] : 0;
    __syncthreads();
    s[t] += u; __syncthreads();
  }
  if (i < NN) incl[i] = s[t];
  if (t == 255) bsum[blockIdx.x] = s[255];
}

__global__ void k_scan2(int* __restrict__ bsum, int nb) {
  __shared__ int s[512];
  int t = threadIdx.x;
  int v = (t < nb) ? bsum[t] : 0;
  s[t] = v; __syncthreads();
  for (int off = 1; off < 512; off <<= 1) {
    int u = (t >= off) ? s[t - off] : 0;
    __syncthreads();
    s[t] += u; __syncthreads();
  }
  if (t < nb) bsum[t] = s[t] - v;  // exclusive block offsets
}

__global__ void k_scan3(const int* __restrict__ incl, const int* __restrict__ deg,
                        const int* __restrict__ bsum, int* __restrict__ rowstart) {
  int i = blockIdx.x * 256 + threadIdx.x;
  if (i < NN) {
    int ex = incl[i] - deg[i] + bsum[blockIdx.x];
    rowstart[i] = ex;
    if (i == NN - 1) rowstart[NN] = ex + deg[i];
  }
}

// ---------------- phase B: scatter within L2-resident group slice -----------
// group g reads its 1.6MB bucket + writes its 800KB col slice: fits 4MB L2.
__global__ __launch_bounds__(256) void k_scatter(const u64* __restrict__ bkt,
    const int* __restrict__ bcur, const int* __restrict__ rowstart,
    int* __restrict__ cursor, int* __restrict__ col) {
  int g = blockIdx.x & (NGRP - 1);
  int cnt = bcur[g * 16]; if (cnt > BCAP) cnt = BCAP;
  int e0 = (blockIdx.x >> 3) * 2048 + threadIdx.x;
  #pragma unroll
  for (int r = 0; r < 8; ++r) {
    int i = e0 + r * 256;
    if (i < cnt) {
      u64 pdv = __builtin_nontemporal_load(&bkt[(size_t)g * BCAP + i]);
      int d = (int)(pdv >> 32), s = (int)(pdv & 0xffffffffu);
      int p = atomicAdd(&cursor[d], 1);
      col[rowstart[d] + p] = s;
    }
  }
}

// ---------------- W (k-major [k][n]) -> Wt (n-major [n][k]) bf16, 4 mats ----
__global__ void k_cvt_wt4(const float* __restrict__ W0, const float* __restrict__ W1,
                          const float* __restrict__ W2, const float* __restrict__ W3,
                          u16* __restrict__ T0, u16* __restrict__ T1,
                          u16* __restrict__ T2, u16* __restrict__ T3) {
  const float* W = blockIdx.y == 0 ? W0 : blockIdx.y == 1 ? W1 : blockIdx.y == 2 ? W2 : W3;
  u16* T = blockIdx.y == 0 ? T0 : blockIdx.y == 1 ? T1 : blockIdx.y == 2 ? T2 : T3;
  int n = blockIdx.x, k = threadIdx.x;
  T[n * D + k] = f2b(W[k * D + n]);
}

// ---------------- mean aggregation: wave per node, 4 rows per load ----------
__global__ __launch_bounds__(256) void k_agg_b(const u16* __restrict__ feat,
    const int* __restrict__ rowstart, const int* __restrict__ col,
    u16* __restrict__ out) {
  int wid = threadIdx.x >> 6;
  int lane = threadIdx.x & 63;
  int node = blockIdx.x * 4 + wid;
  if (node >= NN) return;
  int b = rowstart[node], e = rowstart[node + 1];
  int q = lane >> 4;
  int fl = lane & 15;
  float a[8] = {};
  int j = b;
  for (; j + 7 < e; j += 8) {       // 8 rows in flight per wave
    int s0 = col[j + q];
    int s1 = col[j + 4 + q];
    u16x8 v0 = *reinterpret_cast<const u16x8*>(&feat[(size_t)s0 * D + fl * 8]);
    u16x8 v1 = *reinterpret_cast<const u16x8*>(&feat[(size_t)s1 * D + fl * 8]);
    #pragma unroll
    for (int t = 0; t < 8; ++t) a[t] += b2f(v0[t]) + b2f(v1[t]);
  }
  if (j + 3 < e) {                  // 4-edge step
    int s0 = col[j + q];
    u16x8 v0 = *reinterpret_cast<const u16x8*>(&feat[(size_t)s0 * D + fl * 8]);
    #pragma unroll
    for (int t = 0; t < 8; ++t) a[t] += b2f(v0[t]);
    j += 4;
  }
  if (j + q < e) {                  // tail 1..3 edges (masked per quarter)
    int s0 = col[j + q];
    u16x8 v0 = *reinterpret_cast<const u16x8*>(&feat[(size_t)s0 * D + fl * 8]);
    #pragma unroll
    for (int t = 0; t < 8; ++t) a[t] += b2f(v0[t]);
  }
  #pragma unroll
  for (int t = 0; t < 8; ++t) {     // sum the 4 quarters
    a[t] += __shfl_xor(a[t], 16, 64);
    a[t] += __shfl_xor(a[t], 32, 64);
  }
  if (q == 0) {
    float inv = (e > b) ? 1.f / (float)(e - b) : 0.f;
    u16x8 o;
    #pragma unroll
    for (int t = 0; t < 8; ++t) o[t] = f2b(a[t] * inv);
    *reinterpret_cast<u16x8*>(&out[(size_t)node * D + fl * 8]) = o;
  }
}

// ---------------- fused dual GEMM via MFMA, weights staged in LDS -----------
__global__ __launch_bounds__(256) void k_gemm_mfma(
    const u16* __restrict__ A, const u16* __restrict__ B,
    const u16* __restrict__ Wt1, const u16* __restrict__ Wt2,
    const float* __restrict__ bias, u16* __restrict__ Cout)
{
  __shared__ u16 wlds[128 * WSTRIDE];
  const int t = threadIdx.x;
  const int wid = t >> 6, lane = t & 63;
  const int l15 = lane & 15, g = lane >> 4;
  const int rbase = blockIdx.x * 128 + wid * 32;

  int r0 = rbase + l15, r1 = r0 + 16;
  size_t a0 = (size_t)(r0 < NN ? r0 : NN - 1) * D + g * 8;
  size_t a1 = (size_t)(r1 < NN ? r1 : NN - 1) * D + g * 8;

  f32x4 acc0[8] = {}, acc1[8] = {};

  #pragma unroll
  for (int phase = 0; phase < 2; ++phase) {
    const u16* Act = phase ? B : A;
    const u16* Wt  = phase ? Wt2 : Wt1;
    #pragma unroll
    for (int q = 0; q < 8; ++q) {
      int i = q * 256 + t;           // 16B chunk id, 2048 total
      int n = i >> 4, kc = i & 15;
      *reinterpret_cast<u16x8*>(&wlds[n * WSTRIDE + kc * 8]) =
          *reinterpret_cast<const u16x8*>(&Wt[n * D + kc * 8]);
    }
    __syncthreads();
    #pragma unroll
    for (int kb = 0; kb < 4; ++kb) {
      bf16x8 af0 = *reinterpret_cast<const bf16x8*>(&Act[a0 + kb * 32]);
      bf16x8 af1 = *reinterpret_cast<const bf16x8*>(&Act[a1 + kb * 32]);
      #pragma unroll
      for (int c = 0; c < 8; ++c) {
        bf16x8 wf = *reinterpret_cast<const bf16x8*>(
            &wlds[(c * 16 + l15) * WSTRIDE + kb * 32 + g * 8]);
        acc0[c] = __builtin_amdgcn_mfma_f32_16x16x32_bf16(af0, wf, acc0[c], 0, 0, 0);
        acc1[c] = __builtin_amdgcn_mfma_f32_16x16x32_bf16(af1, wf, acc1[c], 0, 0, 0);
      }
    }
    __syncthreads();   // all waves done reading before restage
  }

  #pragma unroll
  for (int c = 0; c < 8; ++c) {
    float bv = bias[c * 16 + l15];
    #pragma unroll
    for (int r = 0; r < 4; ++r) {
      int row0 = rbase + g * 4 + r;
      if (row0 < NN) {
        float v = fmaxf(acc0[c][r] + bv, 0.f);
        Cout[(size_t)row0 * D + c * 16 + l15] = f2b(v);
      }
      int row1 = row0 + 16;
      if (row1 < NN) {
        float v = fmaxf(acc1[c][r] + bv, 0.f);
        Cout[(size_t)row1 * D + c * 16 + l15] = f2b(v);
      }
    }
  }
}

// ---------------- layer-2 GEMM (LDS weights) + fused layer-3 projection -----
__global__ __launch_bounds__(256) void k_gemm2_zr(
    const u16* __restrict__ A, const u16* __restrict__ B,
    const u16* __restrict__ Wt1, const u16* __restrict__ Wt2,
    const float* __restrict__ bias,
    const float* __restrict__ Wl3, const float* __restrict__ Wr3,
    const float* __restrict__ b3,
    float* __restrict__ z, float* __restrict__ r)
{
  __shared__ u16 wlds[128 * WSTRIDE];
  const int t = threadIdx.x;
  const int wid = t >> 6, lane = t & 63;
  const int l15 = lane & 15, g = lane >> 4;
  const int rbase = blockIdx.x * 128 + wid * 32;

  int r0 = rbase + l15, r1 = r0 + 16;
  size_t a0 = (size_t)(r0 < NN ? r0 : NN - 1) * D + g * 8;
  size_t a1 = (size_t)(r1 < NN ? r1 : NN - 1) * D + g * 8;

  f32x4 acc0[8] = {}, acc1[8] = {};

  #pragma unroll
  for (int phase = 0; phase < 2; ++phase) {
    const u16* Act = phase ? B : A;
    const u16* Wt  = phase ? Wt2 : Wt1;
    #pragma unroll
    for (int q = 0; q < 8; ++q) {
      int i = q * 256 + t;
      int n = i >> 4, kc = i & 15;
      *reinterpret_cast<u16x8*>(&wlds[n * WSTRIDE + kc * 8]) =
          *reinterpret_cast<const u16x8*>(&Wt[n * D + kc * 8]);
    }
    __syncthreads();
    #pragma unroll
    for (int kb = 0; kb < 4; ++kb) {
      bf16x8 af0 = *reinterpret_cast<const bf16x8*>(&Act[a0 + kb * 32]);
      bf16x8 af1 = *reinterpret_cast<const bf16x8*>(&Act[a1 + kb * 32]);
      #pragma unroll
      for (int c = 0; c < 8; ++c) {
        bf16x8 wf = *reinterpret_cast<const bf16x8*>(
            &wlds[(c * 16 + l15) * WSTRIDE + kb * 32 + g * 8]);
        acc0[c] = __builtin_amdgcn_mfma_f32_16x16x32_bf16(af0, wf, acc0[c], 0, 0, 0);
        acc1[c] = __builtin_amdgcn_mfma_f32_16x16x32_bf16(af1, wf, acc1[c], 0, 0, 0);
      }
    }
    __syncthreads();
  }

  float wl[8], wr[8], bv[8];
  #pragma unroll
  for (int c = 0; c < 8; ++c) {
    wl[c] = Wl3[c * 16 + l15];
    wr[c] = Wr3[c * 16 + l15];
    bv[c] = bias[c * 16 + l15];
  }
  float bb3 = b3[0];
  #pragma unroll
  for (int rf = 0; rf < 2; ++rf) {
    #pragma unroll
    for (int rr = 0; rr < 4; ++rr) {
      float pz = 0.f, pr = 0.f;
      #pragma unroll
      for (int c = 0; c < 8; ++c) {
        float v = fmaxf((rf ? acc1[c][rr] : acc0[c][rr]) + bv[c], 0.f);
        pz += v * wl[c];
        pr += v * wr[c];
      }
      pz += __shfl_xor(pz, 1, 64); pr += __shfl_xor(pr, 1, 64);
      pz += __shfl_xor(pz, 2, 64); pr += __shfl_xor(pr, 2, 64);
      pz += __shfl_xor(pz, 4, 64); pr += __shfl_xor(pr, 4, 64);
      pz += __shfl_xor(pz, 8, 64); pr += __shfl_xor(pr, 8, 64);
      int row = rbase + rf * 16 + g * 4 + rr;
      if (l15 == 0 && row < NN) {
        z[row] = pz;
        r[row] = pr + bb3;
      }
    }
  }
}

// ---------------- final: out = r + mean(z over neighbors), 16 lanes/node ----
__global__ __launch_bounds__(256) void k_out(const float* __restrict__ z,
    const float* __restrict__ r, const int* __restrict__ rowstart,
    const int* __restrict__ col, float* __restrict__ out) {
  int t = threadIdx.x;
  int sub = t & 15;
  int node = blockIdx.x * 16 + (t >> 4);
  if (node >= NN) return;
  int b = rowstart[node], e = rowstart[node + 1];
  float s = 0.f;
  for (int j = b + sub; j < e; j += 16) s += z[col[j]];
  s += __shfl_xor(s, 1, 64);
  s += __shfl_xor(s, 2, 64);
  s += __shfl_xor(s, 4, 64);
  s += __shfl_xor(s, 8, 64);
  if (sub == 0) {
    float inv = (e > b) ? 1.f / (float)(e - b) : 0.f;
    out[node] = r[node] + s * inv;
  }
}

extern "C" void kernel_launch(void* const* d_in, const int* in_sizes, int n_in,
                              void* d_out, int out_size, void* d_ws, size_t ws_size,
                              hipStream_t stream) {
  const float* x   = (const float*)d_in[0];
  const int*   ei  = (const int*)d_in[1];
  const float* Wl1 = (const float*)d_in[2];
  const float* Wr1 = (const float*)d_in[3];
  const float* b1  = (const float*)d_in[4];
  const float* Wl2 = (const float*)d_in[5];
  const float* Wr2 = (const float*)d_in[6];
  const float* b2  = (const float*)d_in[7];
  const float* Wl3 = (const float*)d_in[8];
  const float* Wr3 = (const float*)d_in[9];
  const float* b3  = (const float*)d_in[10];
  const int* srcv = ei;
  const int* dstv = ei + NE;
  float* out = (float*)d_out;

  char* ws = (char*)d_ws;
  size_t off = 0;
  auto alloc = [&](size_t bytes) {
    size_t o = off;
    off += (bytes + 255) & ~(size_t)255;
    return o;
  };
  // deg + cursor + bcur contiguous (single memset)
  int* deg      = (int*)(ws + alloc((size_t)(2 * NN + 256) * 4));
  int* cursor   = deg + NN;
  int* bcur     = deg + 2 * NN;          // 8 counters, stride 16 ints (64B)
  int* incl     = (int*)(ws + alloc((size_t)NN * 4));
  int* rowstart = (int*)(ws + alloc((size_t)(NN + 1) * 4));
  int* col      = (int*)(ws + alloc((size_t)NE * 4));
  int* bsum     = (int*)(ws + alloc(512 * 4));
  u64* bkt  = (u64*)(ws + alloc((size_t)NGRP * BCAP * 8));
  u16* xb   = (u16*)(ws + alloc((size_t)NN * D * 2));
  u16* Ab   = (u16*)(ws + alloc((size_t)NN * D * 2));
  u16* H1b  = (u16*)(ws + alloc((size_t)NN * D * 2));
  u16* Wt1l = (u16*)(ws + alloc((size_t)D * D * 2));
  u16* Wt1r = (u16*)(ws + alloc((size_t)D * D * 2));
  u16* Wt2l = (u16*)(ws + alloc((size_t)D * D * 2));
  u16* Wt2r = (u16*)(ws + alloc((size_t)D * D * 2));
  float* z  = (float*)(ws + alloc((size_t)NN * 4));
  float* r  = (float*)(ws + alloc((size_t)NN * 4));

  const int nb_nodes = (NN + 255) / 256;                 // 391
  const int nb_edges = (NE + 255) / 256;                 // 6250
  const int nb_gemm  = (NN + 127) / 128;                 // 782
  const int nb_wave4 = (NN + 3) / 4;                     // 25000
  const int nb_out   = (NN + 15) / 16;                   // 6250
  const int nb_part  = (NE + 256 * EPT - 1) / (256 * EPT);  // 782
  const int nb_bkt   = NGRP * ((BCAP + 2047) / 2048);    // 8*102

  hipMemsetAsync(deg, 0, (size_t)(2 * NN + 256) * 4, stream);

  // CSR build: partition -> local deg count -> scan -> local scatter
  k_cvt<<<nb_edges, 256, 0, stream>>>(x, xb);
  k_part<<<nb_part, 256, 0, stream>>>(srcv, dstv, bkt, bcur);
  k_degcnt<<<nb_bkt, 256, 0, stream>>>(bkt, bcur, deg);
  k_scan1<<<nb_nodes, 256, 0, stream>>>(deg, incl, bsum);
  k_scan2<<<1, 512, 0, stream>>>(bsum, nb_nodes);
  k_scan3<<<nb_nodes, 256, 0, stream>>>(incl, deg, bsum, rowstart);
  k_scatter<<<nb_bkt, 256, 0, stream>>>(bkt, bcur, rowstart, cursor, col);

  // weight prep (transposed bf16)
  k_cvt_wt4<<<dim3(D, 4), D, 0, stream>>>(Wl1, Wr1, Wl2, Wr2, Wt1l, Wt1r, Wt2l, Wt2r);

  // layer 1
  k_agg_b<<<nb_wave4, 256, 0, stream>>>(xb, rowstart, col, Ab);
  k_gemm_mfma<<<nb_gemm, 256, 0, stream>>>(Ab, xb, Wt1l, Wt1r, b1, H1b);
  // layer 2 + fused layer-3 projection
  k_agg_b<<<nb_wave4, 256, 0, stream>>>(H1b, rowstart, col, Ab);
  k_gemm2_zr<<<nb_gemm, 256, 0, stream>>>(Ab, H1b, Wt2l, Wt2r, b2, Wl3, Wr3, b3, z, r);
  // final
  k_out<<<nb_out, 256, 0, stream>>>(z, r, rowstart, col, out);
}

// Round 9
// 310.918 us; speedup vs baseline: 1.6908x; 1.6908x over previous
//
#include <hip/hip_runtime.h>
#include <hip/hip_bf16.h>

#define NN 100000
#define NE 1600000
#define D 128
#define NGRP 8
#define GSZ (NN / NGRP)          // 12500, exact
#define EPT 8                    // edges per thread in hist8/part2
#define NBLK ((NE + 2047) / 2048)   // 782 blocks for hist8/part2
#define NWAVES (NBLK * 4)        // 3128 waves
#define NSUB 32                  // sub-blocks per group in nhist/scatter2
#define WSTRIDE 136              // LDS row stride (u16): 272B -> conflict-free b128

typedef unsigned short u16;
typedef unsigned int u32;
typedef unsigned long long u64;
typedef __attribute__((ext_vector_type(8))) short bf16x8;
typedef __attribute__((ext_vector_type(4))) float f32x4;
typedef __attribute__((ext_vector_type(8))) u16 u16x8;

__device__ inline u16 f2b(float f) {
  union { float f; u32 u; } v; v.f = f;
  u32 u = v.u;
  return (u16)((u + 0x7fffu + ((u >> 16) & 1u)) >> 16);
}
__device__ inline float b2f(u16 h) {
  union { u32 u; float f; } v; v.u = ((u32)h) << 16; return v.f;
}

// ---------------- x -> bf16 convert, pure streaming -------------------------
__global__ __launch_bounds__(256) void k_cvt(const float* __restrict__ xin,
                                             u16* __restrict__ xb) {
  int e = blockIdx.x * 256 + threadIdx.x;      // 1.6M exactly
  const f32x4* p = reinterpret_cast<const f32x4*>(xin) + (size_t)e * 2;
  f32x4 a = __builtin_nontemporal_load(p);
  f32x4 b = __builtin_nontemporal_load(p + 1);
  u16x8 o;
  o[0] = f2b(a[0]); o[1] = f2b(a[1]); o[2] = f2b(a[2]); o[3] = f2b(a[3]);
  o[4] = f2b(b[0]); o[5] = f2b(b[1]); o[6] = f2b(b[2]); o[7] = f2b(b[3]);
  __builtin_nontemporal_store(o, reinterpret_cast<u16x8*>(xb + (size_t)e * 8));
}

// ---------------- per-wave 8-bucket histogram (ballots, no atomics) ---------
__global__ __launch_bounds__(256) void k_hist8(const int* __restrict__ dst,
                                               int* __restrict__ hw) {
  const int t = threadIdx.x, lane = t & 63, wid = t >> 6;
  const int eb = blockIdx.x * (256 * EPT);
  const int wv = blockIdx.x * 4 + wid;
  int c0=0,c1=0,c2=0,c3=0,c4=0,c5=0,c6=0,c7=0;
  #pragma unroll
  for (int r = 0; r < EPT; ++r) {
    int e = eb + r * 256 + t;
    int q = (e < NE) ? __builtin_nontemporal_load(&dst[e]) / GSZ : 8;
    c0 += __popcll(__ballot(q == 0)); c1 += __popcll(__ballot(q == 1));
    c2 += __popcll(__ballot(q == 2)); c3 += __popcll(__ballot(q == 3));
    c4 += __popcll(__ballot(q == 4)); c5 += __popcll(__ballot(q == 5));
    c6 += __popcll(__ballot(q == 6)); c7 += __popcll(__ballot(q == 7));
  }
  if (lane == 0) {
    hw[0 * NWAVES + wv] = c0; hw[1 * NWAVES + wv] = c1;
    hw[2 * NWAVES + wv] = c2; hw[3 * NWAVES + wv] = c3;
    hw[4 * NWAVES + wv] = c4; hw[5 * NWAVES + wv] = c5;
    hw[6 * NWAVES + wv] = c6; hw[7 * NWAVES + wv] = c7;
  }
}

// ---------------- single-block exclusive scan (in place) --------------------
__global__ void k_hscan(int* __restrict__ a, int n) {
  __shared__ int s[256];
  int t = threadIdx.x;
  int per = (n + 255) / 256;
  int lo = t * per, hi = lo + per; if (hi > n) hi = n;
  int sum = 0;
  for (int i = lo; i < hi; ++i) sum += a[i];
  s[t] = sum; __syncthreads();
  for (int off = 1; off < 256; off <<= 1) {
    int u = (t >= off) ? s[t - off] : 0;
    __syncthreads(); s[t] += u; __syncthreads();
  }
  int run = s[t] - sum;
  for (int i = lo; i < hi; ++i) { int v = a[i]; a[i] = run; run += v; }
}

// ---------------- deterministic bucket write (ballot ranks, no atomics) -----
__global__ __launch_bounds__(256) void k_part2(const int* __restrict__ src,
    const int* __restrict__ dst, const int* __restrict__ hw,
    u64* __restrict__ bkt) {
  const int t = threadIdx.x, lane = t & 63, wid = t >> 6;
  const int eb = blockIdx.x * (256 * EPT);
  const int wv = blockIdx.x * 4 + wid;
  int q[EPT]; u32 pd[EPT], ps[EPT];
  #pragma unroll
  for (int r = 0; r < EPT; ++r) {
    int e = eb + r * 256 + t;
    bool v = e < NE;
    int d = v ? __builtin_nontemporal_load(&dst[e]) : 0;
    int s = v ? __builtin_nontemporal_load(&src[e]) : 0;
    q[r] = v ? d / GSZ : 8;
    pd[r] = (u32)d; ps[r] = (u32)s;
  }
  u64 below = (lane == 63) ? 0x7fffffffffffffffull : ((1ull << lane) - 1);
  int base[NGRP];
  #pragma unroll
  for (int b = 0; b < NGRP; ++b) base[b] = hw[b * NWAVES + wv];
  #pragma unroll
  for (int b = 0; b < NGRP; ++b) {
    int run = 0;
    #pragma unroll
    for (int r = 0; r < EPT; ++r) {
      u64 m = __ballot(q[r] == b);
      if (q[r] == b) {
        int pos = base[b] + run + __popcll(m & below);
        if (pos < NE)
          bkt[pos] = ((u64)pd[r] << 32) | ps[r];
      }
      run += __popcll(m);
    }
  }
}

// ---------------- per-sub-block node histogram in LDS -----------------------
__global__ __launch_bounds__(256) void k_nhist(const u64* __restrict__ bkt,
    const int* __restrict__ hw, u16* __restrict__ ncnt) {
  __shared__ int h[GSZ];
  const int g = blockIdx.x & (NGRP - 1);
  const int sub = blockIdx.x >> 3;
  const int t = threadIdx.x;
  const int start = hw[g * NWAVES];
  const int end = (g < NGRP - 1) ? hw[(g + 1) * NWAVES] : NE;
  const int cnt = end - start;
  const int chunk = (cnt + NSUB - 1) / NSUB;
  int lo = start + sub * chunk;
  int hi = lo + chunk; if (hi > end) hi = end;
  for (int i = t; i < GSZ; i += 256) h[i] = 0;
  __syncthreads();
  for (int i = lo + t; i < hi; i += 256) {
    int d = (int)(bkt[i] >> 32);
    atomicAdd(&h[d - g * GSZ], 1);
  }
  __syncthreads();
  u16* outp = ncnt + ((size_t)g * NSUB + sub) * GSZ;
  for (int i = t; i < GSZ; i += 256) outp[i] = (u16)h[i];
}

// ---------------- per-node scan over sub-blocks -> offsets + deg ------------
__global__ __launch_bounds__(256) void k_nscan(u16* __restrict__ ncnt,
    int* __restrict__ deg) {
  const int g = blockIdx.x & (NGRP - 1);
  const int seg = blockIdx.x >> 3;
  int d = seg * 256 + threadIdx.x;
  if (d >= GSZ) return;
  int run = 0;
  #pragma unroll
  for (int s = 0; s < NSUB; ++s) {
    size_t idx = ((size_t)g * NSUB + s) * GSZ + d;
    int v = ncnt[idx];
    ncnt[idx] = (u16)run;
    run += v;
  }
  deg[g * GSZ + d] = run;
}

__global__ void k_scan1(const int* __restrict__ deg, int* __restrict__ incl,
                        int* __restrict__ bsum) {
  __shared__ int s[256];
  int t = threadIdx.x;
  int i = blockIdx.x * 256 + t;
  int v = (i < NN) ? deg[i] : 0;
  s[t] = v; __syncthreads();
  for (int off = 1; off < 256; off <<= 1) {
    int u = (t >= off) ? s[t - off] : 0;
    __syncthreads();
    s[t] += u; __syncthreads();
  }
  if (i < NN) incl[i] = s[t];
  if (t == 255) bsum[blockIdx.x] = s[255];
}

__global__ void k_scan2(int* __restrict__ bsum, int nb) {
  __shared__ int s[512];
  int t = threadIdx.x;
  int v = (t < nb) ? bsum[t] : 0;
  s[t] = v; __syncthreads();
  for (int off = 1; off < 512; off <<= 1) {
    int u = (t >= off) ? s[t - off] : 0;
    __syncthreads();
    s[t] += u; __syncthreads();
  }
  if (t < nb) bsum[t] = s[t] - v;  // exclusive block offsets
}

__global__ void k_scan3(const int* __restrict__ incl, const int* __restrict__ deg,
                        const int* __restrict__ bsum, int* __restrict__ rowstart) {
  int i = blockIdx.x * 256 + threadIdx.x;
  if (i < NN) {
    int ex = incl[i] - deg[i] + bsum[blockIdx.x];
    rowstart[i] = ex;
    if (i == NN - 1) rowstart[NN] = ex + deg[i];
  }
}

// ---------------- scatter: LDS cursors, XCD-resident col slice --------------
__global__ __launch_bounds__(256) void k_scatter2(const u64* __restrict__ bkt,
    const int* __restrict__ hw, const u16* __restrict__ ncnt,
    const int* __restrict__ rowstart, int* __restrict__ col) {
  __shared__ int cur[GSZ];
  const int g = blockIdx.x & (NGRP - 1);
  const int sub = blockIdx.x >> 3;
  const int t = threadIdx.x;
  const int start = hw[g * NWAVES];
  const int end = (g < NGRP - 1) ? hw[(g + 1) * NWAVES] : NE;
  const int cnt = end - start;
  const int chunk = (cnt + NSUB - 1) / NSUB;
  int lo = start + sub * chunk;
  int hi = lo + chunk; if (hi > end) hi = end;
  const u16* nof = ncnt + ((size_t)g * NSUB + sub) * GSZ;
  for (int i = t; i < GSZ; i += 256)
    cur[i] = rowstart[g * GSZ + i] + (int)nof[i];
  __syncthreads();
  for (int i = lo + t; i < hi; i += 256) {
    u64 v = bkt[i];
    int d = (int)(v >> 32), s = (int)(v & 0xffffffffu);
    int pos = atomicAdd(&cur[d - g * GSZ], 1);
    col[pos] = s;
  }
}

// ---------------- W (k-major [k][n]) -> Wt (n-major [n][k]) bf16, 4 mats ----
__global__ void k_cvt_wt4(const float* __restrict__ W0, const float* __restrict__ W1,
                          const float* __restrict__ W2, const float* __restrict__ W3,
                          u16* __restrict__ T0, u16* __restrict__ T1,
                          u16* __restrict__ T2, u16* __restrict__ T3) {
  const float* W = blockIdx.y == 0 ? W0 : blockIdx.y == 1 ? W1 : blockIdx.y == 2 ? W2 : W3;
  u16* T = blockIdx.y == 0 ? T0 : blockIdx.y == 1 ? T1 : blockIdx.y == 2 ? T2 : T3;
  int n = blockIdx.x, k = threadIdx.x;
  T[n * D + k] = f2b(W[k * D + n]);
}

// ---------------- mean aggregation: wave per node, 4 rows per load ----------
__global__ __launch_bounds__(256) void k_agg_b(const u16* __restrict__ feat,
    const int* __restrict__ rowstart, const int* __restrict__ col,
    u16* __restrict__ out) {
  int wid = threadIdx.x >> 6;
  int lane = threadIdx.x & 63;
  int node = blockIdx.x * 4 + wid;
  if (node >= NN) return;
  int b = rowstart[node], e = rowstart[node + 1];
  int q = lane >> 4;
  int fl = lane & 15;
  float a[8] = {};
  int j = b;
  for (; j + 7 < e; j += 8) {       // 8 rows in flight per wave
    int s0 = col[j + q];
    int s1 = col[j + 4 + q];
    u16x8 v0 = *reinterpret_cast<const u16x8*>(&feat[(size_t)s0 * D + fl * 8]);
    u16x8 v1 = *reinterpret_cast<const u16x8*>(&feat[(size_t)s1 * D + fl * 8]);
    #pragma unroll
    for (int t = 0; t < 8; ++t) a[t] += b2f(v0[t]) + b2f(v1[t]);
  }
  if (j + 3 < e) {                  // 4-edge step
    int s0 = col[j + q];
    u16x8 v0 = *reinterpret_cast<const u16x8*>(&feat[(size_t)s0 * D + fl * 8]);
    #pragma unroll
    for (int t = 0; t < 8; ++t) a[t] += b2f(v0[t]);
    j += 4;
  }
  if (j + q < e) {                  // tail 1..3 edges (masked per quarter)
    int s0 = col[j + q];
    u16x8 v0 = *reinterpret_cast<const u16x8*>(&feat[(size_t)s0 * D + fl * 8]);
    #pragma unroll
    for (int t = 0; t < 8; ++t) a[t] += b2f(v0[t]);
  }
  #pragma unroll
  for (int t = 0; t < 8; ++t) {     // sum the 4 quarters
    a[t] += __shfl_xor(a[t], 16, 64);
    a[t] += __shfl_xor(a[t], 32, 64);
  }
  if (q == 0) {
    float inv = (e > b) ? 1.f / (float)(e - b) : 0.f;
    u16x8 o;
    #pragma unroll
    for (int t = 0; t < 8; ++t) o[t] = f2b(a[t] * inv);
    *reinterpret_cast<u16x8*>(&out[(size_t)node * D + fl * 8]) = o;
  }
}

// ---------------- fused dual GEMM via MFMA, weights staged in LDS -----------
__global__ __launch_bounds__(256) void k_gemm_mfma(
    const u16* __restrict__ A, const u16* __restrict__ B,
    const u16* __restrict__ Wt1, const u16* __restrict__ Wt2,
    const float* __restrict__ bias, u16* __restrict__ Cout)
{
  __shared__ u16 wlds[128 * WSTRIDE];
  const int t = threadIdx.x;
  const int wid = t >> 6, lane = t & 63;
  const int l15 = lane & 15, g = lane >> 4;
  const int rbase = blockIdx.x * 128 + wid * 32;

  int r0 = rbase + l15, r1 = r0 + 16;
  size_t a0 = (size_t)(r0 < NN ? r0 : NN - 1) * D + g * 8;
  size_t a1 = (size_t)(r1 < NN ? r1 : NN - 1) * D + g * 8;

  f32x4 acc0[8] = {}, acc1[8] = {};

  #pragma unroll
  for (int phase = 0; phase < 2; ++phase) {
    const u16* Act = phase ? B : A;
    const u16* Wt  = phase ? Wt2 : Wt1;
    #pragma unroll
    for (int q = 0; q < 8; ++q) {
      int i = q * 256 + t;           // 16B chunk id, 2048 total
      int n = i >> 4, kc = i & 15;
      *reinterpret_cast<u16x8*>(&wlds[n * WSTRIDE + kc * 8]) =
          *reinterpret_cast<const u16x8*>(&Wt[n * D + kc * 8]);
    }
    __syncthreads();
    #pragma unroll
    for (int kb = 0; kb < 4; ++kb) {
      bf16x8 af0 = *reinterpret_cast<const bf16x8*>(&Act[a0 + kb * 32]);
      bf16x8 af1 = *reinterpret_cast<const bf16x8*>(&Act[a1 + kb * 32]);
      #pragma unroll
      for (int c = 0; c < 8; ++c) {
        bf16x8 wf = *reinterpret_cast<const bf16x8*>(
            &wlds[(c * 16 + l15) * WSTRIDE + kb * 32 + g * 8]);
        acc0[c] = __builtin_amdgcn_mfma_f32_16x16x32_bf16(af0, wf, acc0[c], 0, 0, 0);
        acc1[c] = __builtin_amdgcn_mfma_f32_16x16x32_bf16(af1, wf, acc1[c], 0, 0, 0);
      }
    }
    __syncthreads();   // all waves done reading before restage
  }

  #pragma unroll
  for (int c = 0; c < 8; ++c) {
    float bv = bias[c * 16 + l15];
    #pragma unroll
    for (int r = 0; r < 4; ++r) {
      int row0 = rbase + g * 4 + r;
      if (row0 < NN) {
        float v = fmaxf(acc0[c][r] + bv, 0.f);
        Cout[(size_t)row0 * D + c * 16 + l15] = f2b(v);
      }
      int row1 = row0 + 16;
      if (row1 < NN) {
        float v = fmaxf(acc1[c][r] + bv, 0.f);
        Cout[(size_t)row1 * D + c * 16 + l15] = f2b(v);
      }
    }
  }
}

// ---------------- layer-2 GEMM (LDS weights) + fused layer-3 projection -----
__global__ __launch_bounds__(256) void k_gemm2_zr(
    const u16* __restrict__ A, const u16* __restrict__ B,
    const u16* __restrict__ Wt1, const u16* __restrict__ Wt2,
    const float* __restrict__ bias,
    const float* __restrict__ Wl3, const float* __restrict__ Wr3,
    const float* __restrict__ b3,
    float* __restrict__ z, float* __restrict__ r)
{
  __shared__ u16 wlds[128 * WSTRIDE];
  const int t = threadIdx.x;
  const int wid = t >> 6, lane = t & 63;
  const int l15 = lane & 15, g = lane >> 4;
  const int rbase = blockIdx.x * 128 + wid * 32;

  int r0 = rbase + l15, r1 = r0 + 16;
  size_t a0 = (size_t)(r0 < NN ? r0 : NN - 1) * D + g * 8;
  size_t a1 = (size_t)(r1 < NN ? r1 : NN - 1) * D + g * 8;

  f32x4 acc0[8] = {}, acc1[8] = {};

  #pragma unroll
  for (int phase = 0; phase < 2; ++phase) {
    const u16* Act = phase ? B : A;
    const u16* Wt  = phase ? Wt2 : Wt1;
    #pragma unroll
    for (int q = 0; q < 8; ++q) {
      int i = q * 256 + t;
      int n = i >> 4, kc = i & 15;
      *reinterpret_cast<u16x8*>(&wlds[n * WSTRIDE + kc * 8]) =
          *reinterpret_cast<const u16x8*>(&Wt[n * D + kc * 8]);
    }
    __syncthreads();
    #pragma unroll
    for (int kb = 0; kb < 4; ++kb) {
      bf16x8 af0 = *reinterpret_cast<const bf16x8*>(&Act[a0 + kb * 32]);
      bf16x8 af1 = *reinterpret_cast<const bf16x8*>(&Act[a1 + kb * 32]);
      #pragma unroll
      for (int c = 0; c < 8; ++c) {
        bf16x8 wf = *reinterpret_cast<const bf16x8*>(
            &wlds[(c * 16 + l15) * WSTRIDE + kb * 32 + g * 8]);
        acc0[c] = __builtin_amdgcn_mfma_f32_16x16x32_bf16(af0, wf, acc0[c], 0, 0, 0);
        acc1[c] = __builtin_amdgcn_mfma_f32_16x16x32_bf16(af1, wf, acc1[c], 0, 0, 0);
      }
    }
    __syncthreads();
  }

  float wl[8], wr[8], bv[8];
  #pragma unroll
  for (int c = 0; c < 8; ++c) {
    wl[c] = Wl3[c * 16 + l15];
    wr[c] = Wr3[c * 16 + l15];
    bv[c] = bias[c * 16 + l15];
  }
  float bb3 = b3[0];
  #pragma unroll
  for (int rf = 0; rf < 2; ++rf) {
    #pragma unroll
    for (int rr = 0; rr < 4; ++rr) {
      float pz = 0.f, pr = 0.f;
      #pragma unroll
      for (int c = 0; c < 8; ++c) {
        float v = fmaxf((rf ? acc1[c][rr] : acc0[c][rr]) + bv[c], 0.f);
        pz += v * wl[c];
        pr += v * wr[c];
      }
      pz += __shfl_xor(pz, 1, 64); pr += __shfl_xor(pr, 1, 64);
      pz += __shfl_xor(pz, 2, 64); pr += __shfl_xor(pr, 2, 64);
      pz += __shfl_xor(pz, 4, 64); pr += __shfl_xor(pr, 4, 64);
      pz += __shfl_xor(pz, 8, 64); pr += __shfl_xor(pr, 8, 64);
      int row = rbase + rf * 16 + g * 4 + rr;
      if (l15 == 0 && row < NN) {
        z[row] = pz;
        r[row] = pr + bb3;
      }
    }
  }
}

// ---------------- final: out = r + mean(z over neighbors), 16 lanes/node ----
__global__ __launch_bounds__(256) void k_out(const float* __restrict__ z,
    const float* __restrict__ r, const int* __restrict__ rowstart,
    const int* __restrict__ col, float* __restrict__ out) {
  int t = threadIdx.x;
  int sub = t & 15;
  int node = blockIdx.x * 16 + (t >> 4);
  if (node >= NN) return;
  int b = rowstart[node], e = rowstart[node + 1];
  float s = 0.f;
  for (int j = b + sub; j < e; j += 16) s += z[col[j]];
  s += __shfl_xor(s, 1, 64);
  s += __shfl_xor(s, 2, 64);
  s += __shfl_xor(s, 4, 64);
  s += __shfl_xor(s, 8, 64);
  if (sub == 0) {
    float inv = (e > b) ? 1.f / (float)(e - b) : 0.f;
    out[node] = r[node] + s * inv;
  }
}

extern "C" void kernel_launch(void* const* d_in, const int* in_sizes, int n_in,
                              void* d_out, int out_size, void* d_ws, size_t ws_size,
                              hipStream_t stream) {
  const float* x   = (const float*)d_in[0];
  const int*   ei  = (const int*)d_in[1];
  const float* Wl1 = (const float*)d_in[2];
  const float* Wr1 = (const float*)d_in[3];
  const float* b1  = (const float*)d_in[4];
  const float* Wl2 = (const float*)d_in[5];
  const float* Wr2 = (const float*)d_in[6];
  const float* b2  = (const float*)d_in[7];
  const float* Wl3 = (const float*)d_in[8];
  const float* Wr3 = (const float*)d_in[9];
  const float* b3  = (const float*)d_in[10];
  const int* srcv = ei;
  const int* dstv = ei + NE;
  float* out = (float*)d_out;

  char* ws = (char*)d_ws;
  size_t off = 0;
  auto alloc = [&](size_t bytes) {
    size_t o = off;
    off += (bytes + 255) & ~(size_t)255;
    return o;
  };
  int* deg      = (int*)(ws + alloc((size_t)NN * 4));
  int* incl     = (int*)(ws + alloc((size_t)NN * 4));
  int* rowstart = (int*)(ws + alloc((size_t)(NN + 1) * 4));
  int* col      = (int*)(ws + alloc((size_t)NE * 4));
  int* bsum     = (int*)(ws + alloc(512 * 4));
  int* hw       = (int*)(ws + alloc((size_t)NGRP * NWAVES * 4));
  u64* bkt  = (u64*)(ws + alloc((size_t)NE * 8));
  u16* ncnt = (u16*)(ws + alloc((size_t)NGRP * NSUB * GSZ * 2));
  u16* xb   = (u16*)(ws + alloc((size_t)NN * D * 2));
  u16* Ab   = (u16*)(ws + alloc((size_t)NN * D * 2));
  u16* H1b  = (u16*)(ws + alloc((size_t)NN * D * 2));
  u16* Wt1l = (u16*)(ws + alloc((size_t)D * D * 2));
  u16* Wt1r = (u16*)(ws + alloc((size_t)D * D * 2));
  u16* Wt2l = (u16*)(ws + alloc((size_t)D * D * 2));
  u16* Wt2r = (u16*)(ws + alloc((size_t)D * D * 2));
  float* z  = (float*)(ws + alloc((size_t)NN * 4));
  float* r  = (float*)(ws + alloc((size_t)NN * 4));

  const int nb_nodes = (NN + 255) / 256;     // 391
  const int nb_edges = (NE + 255) / 256;     // 6250
  const int nb_gemm  = (NN + 127) / 128;     // 782
  const int nb_wave4 = (NN + 3) / 4;         // 25000
  const int nb_out   = (NN + 15) / 16;       // 6250
  const int nb_sub   = NGRP * NSUB;          // 256
  const int nb_nscan = NGRP * ((GSZ + 255) / 256);  // 8*49

  // atomic-free CSR build
  k_cvt<<<nb_edges, 256, 0, stream>>>(x, xb);
  k_hist8<<<NBLK, 256, 0, stream>>>(dstv, hw);
  k_hscan<<<1, 256, 0, stream>>>(hw, NGRP * NWAVES);
  k_part2<<<NBLK, 256, 0, stream>>>(srcv, dstv, hw, bkt);
  k_nhist<<<nb_sub, 256, 0, stream>>>(bkt, hw, ncnt);
  k_nscan<<<nb_nscan, 256, 0, stream>>>(ncnt, deg);
  k_scan1<<<nb_nodes, 256, 0, stream>>>(deg, incl, bsum);
  k_scan2<<<1, 512, 0, stream>>>(bsum, nb_nodes);
  k_scan3<<<nb_nodes, 256, 0, stream>>>(incl, deg, bsum, rowstart);
  k_scatter2<<<nb_sub, 256, 0, stream>>>(bkt, hw, ncnt, rowstart, col);

  // weight prep (transposed bf16)
  k_cvt_wt4<<<dim3(D, 4), D, 0, stream>>>(Wl1, Wr1, Wl2, Wr2, Wt1l, Wt1r, Wt2l, Wt2r);

  // layer 1
  k_agg_b<<<nb_wave4, 256, 0, stream>>>(xb, rowstart, col, Ab);
  k_gemm_mfma<<<nb_gemm, 256, 0, stream>>>(Ab, xb, Wt1l, Wt1r, b1, H1b);
  // layer 2 + fused layer-3 projection
  k_agg_b<<<nb_wave4, 256, 0, stream>>>(H1b, rowstart, col, Ab);
  k_gemm2_zr<<<nb_gemm, 256, 0, stream>>>(Ab, H1b, Wt2l, Wt2r, b2, Wl3, Wr3, b3, z, r);
  // final
  k_out<<<nb_out, 256, 0, stream>>>(z, r, rowstart, col, out);
}